// Round 7
// baseline (119.905 us; speedup 1.0000x reference)
//
#include <hip/hip_runtime.h>

#define IMG   224
#define IMG2  (IMG*IMG)
#define NN    27          // patches per dim
#define KK    256         // pixels per patch
#define EE    128
#define NSTRIP 28         // output 8-row strips
#define SCOLS 232         // strip row stride in elems
#define RSTR  132         // rec row stride in elems

typedef float f32x4 __attribute__((ext_vector_type(4)));
typedef short s16x8 __attribute__((ext_vector_type(8)));
typedef __bf16 bf16x4 __attribute__((ext_vector_type(4)));

__device__ __forceinline__ uint2 pack4(f32x4 r) {
    // native casts -> compiler fuses to v_cvt_pk_bf16_f32 (RNE)
    bf16x4 h;
    h[0] = (__bf16)r.x; h[1] = (__bf16)r.y; h[2] = (__bf16)r.z; h[3] = (__bf16)r.w;
    uint2 u;
    __builtin_memcpy(&u, &h, 8);
    return u;
}
__device__ __forceinline__ float bf2f(unsigned short us) {
    __bf16 h;
    __builtin_memcpy(&h, &us, 2);
    return (float)h;
}
__device__ __forceinline__ unsigned short f2bf(float f) {
    __bf16 h = (__bf16)f;
    unsigned short us;
    __builtin_memcpy(&us, &h, 2);
    return us;
}

// M[c][k][j] = sum_e W_dec[c][k][e]*W_enc[c][e][j], packed in MFMA A-frag order:
// APK[c][kf(16)][jb(8)][lane(64)][i(8)] = bf16(M[kf*16+(lane&15)][jb*32+8*(lane>>4)+i])
// Also v[c][k] = b_dec[c][k] + sum_e W_dec[c][k][e]*b_enc[c][e].
__global__ void pack_M(const float* __restrict__ W_enc, const float* __restrict__ W_dec,
                       const float* __restrict__ b_enc, const float* __restrict__ b_dec,
                       unsigned short* __restrict__ APK, float* __restrict__ v) {
    int k = blockIdx.x, c = blockIdx.y, j = threadIdx.x;
    const float* wd = W_dec + ((size_t)c*KK + k)*EE;
    const float* we = W_enc + (size_t)c*EE*KK + j;
    float acc = 0.f;
    #pragma unroll 8
    for (int e = 0; e < EE; ++e) acc = fmaf(wd[e], we[(size_t)e*KK], acc);
    int kf = k >> 4, kr = k & 15, jb = j >> 5, g = (j >> 3) & 3, i = j & 7;
    APK[(size_t)c*65536 + (((kf*8 + jb)*64) + g*16 + kr)*8 + i] = f2bf(acc);

    __shared__ float pv[128];
    if (j < EE) pv[j] = wd[j] * b_enc[c*EE + j];
    __syncthreads();
    for (int off = 64; off > 0; off >>= 1) {
        if (j < off) pv[j] += pv[j + off];
        __syncthreads();
    }
    if (j == 0) v[c*KK + k] = pv[0] + b_dec[c*KK + k];
}

__global__ __launch_bounds__(256, 6)
void patch_ae_mfma(const float* __restrict__ x, const unsigned short* __restrict__ APK,
                   const float* __restrict__ v, float* __restrict__ out) {
    // bijective XCD swizzle: 5376 blocks = 8 XCDs x 672
    const int hid = blockIdx.x + NSTRIP*(blockIdx.y + 3*blockIdx.z);
    const int lid = (hid & 7)*672 + (hid >> 3);
    const int s  = lid % NSTRIP;
    const int t2 = lid / NSTRIP;
    const int c  = t2 % 3;
    const int b  = t2 / 3;

    const int tid  = threadIdx.x;
    const int lane = tid & 63, wave = tid >> 6;

    __shared__ __align__(16) unsigned short strip[24*SCOLS];   // 11136 B
    __shared__ __align__(16) unsigned short rec[2][28][RSTR];  // 14784 B (row 27 = dump)
    __shared__ __align__(16) float vsh[256];                   // 1024 B

    vsh[tid] = v[c*256 + tid];

    // wave constants
    const int prow    = wave >> 1;       // 0: ny=s (strip row 8), 1: ny=s-1 (strip row 0)
    const int kq      = wave & 1;
    const int rowbase = prow ? 0 : 8;
    const int kfbase  = prow*8 + kq*4;
    const int g = lane >> 4, lr = lane & 15;
    const s16x8* APKc = (const s16x8*)(APK + (size_t)c*65536);

    // depth-2 A prefetch: jb=0 and jb=1 issued before staging (overlap stage latency)
    s16x8 aN0[4], aN1[4];
    #pragma unroll
    for (int f = 0; f < 4; ++f) aN0[f] = APKc[((kfbase + f)*8 + 0)*64 + lane];
    #pragma unroll
    for (int f = 0; f < 4; ++f) aN1[f] = APKc[((kfbase + f)*8 + 1)*64 + lane];

    // ---- stage input strip rows [8s-8, 8s+16), cols [0,224), f32 -> bf16 ----
    if (tid < 224) {
        const float* xb = x + (size_t)(b*3 + c)*IMG2;
        const int ybase = 8*s - 8;
        const int r0 = tid / 56;          // one div for the whole phase
        const int c4 = tid - r0*56;
        #pragma unroll
        for (int it = 0; it < 6; ++it) {
            int r  = r0 + it*4;
            int yr = ybase + r;
            float4 xv = make_float4(0.f, 0.f, 0.f, 0.f);
            if ((unsigned)yr < IMG)
                xv = ((const float4*)(xb + (size_t)yr*IMG))[c4];
            f32x4 xr = {xv.x, xv.y, xv.z, xv.w};
            *((uint2*)&strip[r*SCOLS + c4*4]) = pack4(xr);
        }
    }
    __syncthreads();

    // ---- MFMA with depth-2 A pipeline ----
    {
        f32x4 acc[4][2];
        #pragma unroll
        for (int f = 0; f < 4; ++f)
            #pragma unroll
            for (int pf = 0; pf < 2; ++pf)
                acc[f][pf] = (f32x4){0.f, 0.f, 0.f, 0.f};

        // pf1 column: patches 16+lr; lanes lr>=11 (p>=27 unused) clamped in-bounds
        const int c1 = (lr <= 10) ? (128 + 8*lr) : 208;

        #pragma unroll
        for (int jb = 0; jb < 8; ++jb) {
            s16x8 aC[4];
            #pragma unroll
            for (int f = 0; f < 4; ++f) aC[f] = aN0[f];
            #pragma unroll
            for (int f = 0; f < 4; ++f) aN0[f] = aN1[f];
            if (jb < 6) {
                #pragma unroll
                for (int f = 0; f < 4; ++f)
                    aN1[f] = APKc[((kfbase + f)*8 + (jb+2))*64 + lane];
            }
            const int jy  = 2*jb + (g >> 1);
            const int jx0 = (g & 1)*8;
            const unsigned short* srow = &strip[(rowbase + jy)*SCOLS + jx0];
            s16x8 bfrag[2];
            bfrag[0] = *((const s16x8*)&srow[8*lr]);
            bfrag[1] = *((const s16x8*)&srow[c1]);
            __builtin_amdgcn_s_setprio(1);
            #pragma unroll
            for (int f = 0; f < 4; ++f) {
                acc[f][0] = __builtin_amdgcn_mfma_f32_16x16x32_bf16(aC[f], bfrag[0], acc[f][0], 0, 0, 0);
                acc[f][1] = __builtin_amdgcn_mfma_f32_16x16x32_bf16(aC[f], bfrag[1], acc[f][1], 0, 0, 0);
            }
            __builtin_amdgcn_s_setprio(0);
        }

        // bias + bf16 store: rec[prow][p][klocal] holds k = prow*128 + klocal
        #pragma unroll
        for (int f = 0; f < 4; ++f) {
            int klocal = kq*64 + f*16 + g*4;
            f32x4 bias = *((const f32x4*)&vsh[prow*128 + klocal]);
            #pragma unroll
            for (int pf = 0; pf < 2; ++pf) {
                f32x4 r = acc[f][pf] + bias;
                int p = min(pf*16 + lr, 27);      // p>=27 -> dump row (never read)
                *((uint2*)&rec[prow][p][klocal]) = pack4(r);
            }
        }
    }
    __syncthreads();

    // ---- combine overlaps, write each pixel once (thread = column, 8 rows) ----
    if (tid < 224) {
        const int xc = tid;
        const int p1 = xc >> 3;
        const int v1 = (p1 <= NN-1);
        const int v0 = (p1 > 0);
        const int p0v = v0 ? p1 - 1 : 0;
        const int dx1 = xc & 7, dx0 = dx1 + 8;
        const int h0 = (s < NSTRIP-1);
        const int h1 = (s > 0);
        const int shift = (v0 & v1) + (h0 & h1);
        const float inv = __int_as_float(0x3f800000 - (shift << 23)); // exact 1/2^shift
        float* orow = out + (size_t)(b*3 + c)*IMG2 + (size_t)(8*s)*IMG + xc;
        #pragma unroll
        for (int ry = 0; ry < 8; ++ry) {
            int kl1 = ry*16 + dx1, kl0 = ry*16 + dx0;
            float sum = 0.f;
            if (v1) {
                if (h0) sum += bf2f(rec[0][p1][kl1]);
                if (h1) sum += bf2f(rec[1][p1][kl1]);
            }
            if (v0) {
                if (h0) sum += bf2f(rec[0][p0v][kl0]);
                if (h1) sum += bf2f(rec[1][p0v][kl0]);
            }
            orow[(size_t)ry*IMG] = sum * inv;
        }
    }
}

extern "C" void kernel_launch(void* const* d_in, const int* in_sizes, int n_in,
                              void* d_out, int out_size, void* d_ws, size_t ws_size,
                              hipStream_t stream) {
    (void)in_sizes; (void)n_in; (void)out_size; (void)ws_size;
    const float* x     = (const float*)d_in[0];
    const float* W_enc = (const float*)d_in[1];
    const float* b_enc = (const float*)d_in[2];
    const float* W_dec = (const float*)d_in[3];
    const float* b_dec = (const float*)d_in[4];
    float* out = (float*)d_out;

    float*          v   = (float*)d_ws;                          // 768 f32
    unsigned short* APK = (unsigned short*)((char*)d_ws + 4096); // 3 x 65536 bf16 = 384 KB

    pack_M<<<dim3(KK, 3), 256, 0, stream>>>(W_enc, W_dec, b_enc, b_dec, APK, v);
    patch_ae_mfma<<<dim3(NSTRIP, 3, 64), 256, 0, stream>>>(x, APK, v, out);
}

// Round 9
// 50.279 us; speedup vs baseline: 2.3848x; 2.3848x over previous
//
#include <hip/hip_runtime.h>

#define IMG   224
#define IMG2  (IMG*IMG)
#define NN    27          // patches per dim
#define KK    256         // pixels per patch
#define EE    128
#define NSTRIP 28         // output 8-row strips
#define SCOLS 232         // strip row stride in elems
#define RSTR  132         // rec row stride in elems

typedef float f32x4 __attribute__((ext_vector_type(4)));
typedef short s16x8 __attribute__((ext_vector_type(8)));

__device__ __forceinline__ unsigned short f2bf(float f) {
    unsigned int u = __float_as_uint(f);
    u = (u + 0x7fffu + ((u >> 16) & 1u)) >> 16;   // RNE (inputs finite)
    return (unsigned short)u;
}
__device__ __forceinline__ float bf2f(unsigned short u) {
    return __uint_as_float((unsigned int)u << 16);
}
// register-only packed cvt (RNE). Single-instruction asm statements: inputs are
// read before dst is written, so no early-clobber hazard (round-8 bug fixed).
__device__ __forceinline__ uint2 pack4(f32x4 r) {
    uint2 u;
    asm("v_cvt_pk_bf16_f32 %0, %1, %2" : "=v"(u.x) : "v"(r.x), "v"(r.y));
    asm("v_cvt_pk_bf16_f32 %0, %1, %2" : "=v"(u.y) : "v"(r.z), "v"(r.w));
    return u;
}

// M[c][k][j] = sum_e W_dec[c][k][e]*W_enc[c][e][j], packed in MFMA A-frag order:
// APK[c][kf(16)][jb(8)][lane(64)][i(8)] = bf16(M[kf*16+(lane&15)][jb*32+8*(lane>>4)+i])
// Also v[c][k] = b_dec[c][k] + sum_e W_dec[c][k][e]*b_enc[c][e].
__global__ void pack_M(const float* __restrict__ W_enc, const float* __restrict__ W_dec,
                       const float* __restrict__ b_enc, const float* __restrict__ b_dec,
                       unsigned short* __restrict__ APK, float* __restrict__ v) {
    int k = blockIdx.x, c = blockIdx.y, j = threadIdx.x;
    const float* wd = W_dec + ((size_t)c*KK + k)*EE;
    const float* we = W_enc + (size_t)c*EE*KK + j;
    float acc = 0.f;
    #pragma unroll 8
    for (int e = 0; e < EE; ++e) acc = fmaf(wd[e], we[(size_t)e*KK], acc);
    int kf = k >> 4, kr = k & 15, jb = j >> 5, g = (j >> 3) & 3, i = j & 7;
    APK[(size_t)c*65536 + (((kf*8 + jb)*64) + g*16 + kr)*8 + i] = f2bf(acc);

    __shared__ float pv[128];
    if (j < EE) pv[j] = wd[j] * b_enc[c*EE + j];
    __syncthreads();
    for (int off = 64; off > 0; off >>= 1) {
        if (j < off) pv[j] += pv[j + off];
        __syncthreads();
    }
    if (j == 0) v[c*KK + k] = pv[0] + b_dec[c*KK + k];
}

__global__ __launch_bounds__(256, 5)
void patch_ae_mfma(const float* __restrict__ x, const unsigned short* __restrict__ APK,
                   const float* __restrict__ v, float* __restrict__ out) {
    // bijective XCD swizzle: 5376 blocks = 8 XCDs x 672
    const int hid = blockIdx.x + NSTRIP*(blockIdx.y + 3*blockIdx.z);
    const int lid = (hid & 7)*672 + (hid >> 3);
    const int s  = lid % NSTRIP;
    const int t2 = lid / NSTRIP;
    const int c  = t2 % 3;
    const int b  = t2 / 3;

    const int tid  = threadIdx.x;
    const int lane = tid & 63, wave = tid >> 6;

    __shared__ __align__(16) unsigned short strip[24*SCOLS];   // 11136 B
    __shared__ __align__(16) unsigned short rec[2][28][RSTR];  // 14784 B (row 27 = dump)
    __shared__ __align__(16) float vsh[256];                   // 1024 B

    vsh[tid] = v[c*256 + tid];

    // wave constants
    const int prow    = wave >> 1;       // 0: ny=s (strip row 8), 1: ny=s-1 (strip row 0)
    const int kq      = wave & 1;
    const int rowbase = prow ? 0 : 8;
    const int kfbase  = prow*8 + kq*4;
    const int g = lane >> 4, lr = lane & 15;
    const s16x8* APKc = (const s16x8*)(APK + (size_t)c*65536);

    // depth-2 A prefetch: jb=0 -> a0, jb=1 -> a1, issued before staging
    s16x8 a0[4], a1[4];
    #pragma unroll
    for (int f = 0; f < 4; ++f) a0[f] = APKc[((kfbase + f)*8 + 0)*64 + lane];
    #pragma unroll
    for (int f = 0; f < 4; ++f) a1[f] = APKc[((kfbase + f)*8 + 1)*64 + lane];

    // ---- stage input strip rows [8s-8, 8s+16), cols [0,224), f32 -> bf16 ----
    if (tid < 224) {
        const float* xb = x + (size_t)(b*3 + c)*IMG2;
        const int ybase = 8*s - 8;
        const int r0 = tid / 56;          // one div for the whole phase
        const int c4 = tid - r0*56;
        #pragma unroll
        for (int it = 0; it < 6; ++it) {
            int r  = r0 + it*4;
            int yr = ybase + r;
            float4 xv = make_float4(0.f, 0.f, 0.f, 0.f);
            if ((unsigned)yr < IMG)
                xv = ((const float4*)(xb + (size_t)yr*IMG))[c4];
            f32x4 xr = {xv.x, xv.y, xv.z, xv.w};
            *((uint2*)&strip[r*SCOLS + c4*4]) = pack4(xr);
        }
    }
    __syncthreads();

    // ---- MFMA with depth-2 alternating-buffer A pipeline (no copies) ----
    {
        f32x4 acc[4][2];
        #pragma unroll
        for (int f = 0; f < 4; ++f)
            #pragma unroll
            for (int pf = 0; pf < 2; ++pf)
                acc[f][pf] = (f32x4){0.f, 0.f, 0.f, 0.f};

        // pf1 column: patches 16+lr; lanes lr>=11 (p>=27 unused) clamped in-bounds
        const int c1 = (lr <= 10) ? (128 + 8*lr) : 208;

        #pragma unroll
        for (int jb = 0; jb < 8; ++jb) {
            const int jy  = 2*jb + (g >> 1);
            const int jx0 = (g & 1)*8;
            const unsigned short* srow = &strip[(rowbase + jy)*SCOLS + jx0];
            s16x8 bf0 = *((const s16x8*)&srow[8*lr]);
            s16x8 bf1 = *((const s16x8*)&srow[c1]);
            if ((jb & 1) == 0) {
                __builtin_amdgcn_s_setprio(1);
                #pragma unroll
                for (int f = 0; f < 4; ++f) {
                    acc[f][0] = __builtin_amdgcn_mfma_f32_16x16x32_bf16(a0[f], bf0, acc[f][0], 0, 0, 0);
                    acc[f][1] = __builtin_amdgcn_mfma_f32_16x16x32_bf16(a0[f], bf1, acc[f][1], 0, 0, 0);
                }
                __builtin_amdgcn_s_setprio(0);
                if (jb < 6) {
                    #pragma unroll
                    for (int f = 0; f < 4; ++f)
                        a0[f] = APKc[((kfbase + f)*8 + (jb+2))*64 + lane];
                }
            } else {
                __builtin_amdgcn_s_setprio(1);
                #pragma unroll
                for (int f = 0; f < 4; ++f) {
                    acc[f][0] = __builtin_amdgcn_mfma_f32_16x16x32_bf16(a1[f], bf0, acc[f][0], 0, 0, 0);
                    acc[f][1] = __builtin_amdgcn_mfma_f32_16x16x32_bf16(a1[f], bf1, acc[f][1], 0, 0, 0);
                }
                __builtin_amdgcn_s_setprio(0);
                if (jb < 6) {
                    #pragma unroll
                    for (int f = 0; f < 4; ++f)
                        a1[f] = APKc[((kfbase + f)*8 + (jb+2))*64 + lane];
                }
            }
        }

        // bias + bf16 store: rec[prow][p][klocal] holds k = prow*128 + klocal
        #pragma unroll
        for (int f = 0; f < 4; ++f) {
            int klocal = kq*64 + f*16 + g*4;
            f32x4 bias = *((const f32x4*)&vsh[prow*128 + klocal]);
            #pragma unroll
            for (int pf = 0; pf < 2; ++pf) {
                f32x4 r = acc[f][pf] + bias;
                int p = min(pf*16 + lr, 27);      // p>=27 -> dump row (never read)
                *((uint2*)&rec[prow][p][klocal]) = pack4(r);
            }
        }
    }
    __syncthreads();

    // ---- combine overlaps, write each pixel once (thread = column, 8 rows) ----
    if (tid < 224) {
        const int xc = tid;
        const int p1 = xc >> 3;
        const int v1 = (p1 <= NN-1);
        const int v0 = (p1 > 0);
        const int p0v = v0 ? p1 - 1 : 0;
        const int dx1 = xc & 7, dx0 = dx1 + 8;
        const int h0 = (s < NSTRIP-1);
        const int h1 = (s > 0);
        const int shift = (v0 & v1) + (h0 & h1);
        const float inv = __int_as_float(0x3f800000 - (shift << 23)); // exact 1/2^shift
        float* orow = out + (size_t)(b*3 + c)*IMG2 + (size_t)(8*s)*IMG + xc;
        #pragma unroll
        for (int ry = 0; ry < 8; ++ry) {
            int kl1 = ry*16 + dx1, kl0 = ry*16 + dx0;
            float sum = 0.f;
            if (v1) {
                if (h0) sum += bf2f(rec[0][p1][kl1]);
                if (h1) sum += bf2f(rec[1][p1][kl1]);
            }
            if (v0) {
                if (h0) sum += bf2f(rec[0][p0v][kl0]);
                if (h1) sum += bf2f(rec[1][p0v][kl0]);
            }
            orow[(size_t)ry*IMG] = sum * inv;
        }
    }
}

extern "C" void kernel_launch(void* const* d_in, const int* in_sizes, int n_in,
                              void* d_out, int out_size, void* d_ws, size_t ws_size,
                              hipStream_t stream) {
    (void)in_sizes; (void)n_in; (void)out_size; (void)ws_size;
    const float* x     = (const float*)d_in[0];
    const float* W_enc = (const float*)d_in[1];
    const float* b_enc = (const float*)d_in[2];
    const float* W_dec = (const float*)d_in[3];
    const float* b_dec = (const float*)d_in[4];
    float* out = (float*)d_out;

    float*          v   = (float*)d_ws;                          // 768 f32
    unsigned short* APK = (unsigned short*)((char*)d_ws + 4096); // 3 x 65536 bf16 = 384 KB

    pack_M<<<dim3(KK, 3), 256, 0, stream>>>(W_enc, W_dec, b_enc, b_dec, APK, v);
    patch_ae_mfma<<<dim3(NSTRIP, 3, 64), 256, 0, stream>>>(x, APK, v, out);
}